// Round 1
// baseline (2448.421 us; speedup 1.0000x reference)
//
#include <hip/hip_runtime.h>

#define NPTS   8192
#define CCH    32
#define LDIM   64
#define ODIM   128
#define KNN    16
#define TILE   128
#define TSTRIDE 36          // floats per LDS tile row (32 data + 4 pad for bank spread)
#define BN_TOTAL (4 * NPTS) // 32768 total query points
#define QPB    8            // queries per block (4 waves x 2)

__global__ __launch_bounds__(256, 2)
void graph_layer_kernel(const float* __restrict__ x,
                        const float* __restrict__ Wl,
                        const float* __restrict__ bl,
                        const float* __restrict__ Wc,
                        const float* __restrict__ bc,
                        float* __restrict__ out)
{
    __shared__ __align__(16) float tile[TILE * TSTRIDE];
    __shared__ float sqbuf[2 * TILE];     // two half-row partial sq per candidate
    __shared__ int   knn_idx[QPB][KNN];
    __shared__ float pooled[QPB][CCH];
    __shared__ float hbuf[QPB][LDIM];

    const int tid  = threadIdx.x;
    const int lane = tid & 63;
    const int wave = tid >> 6;
    const float INF = __builtin_inff();

    const int qbase = blockIdx.x * QPB;          // 8 queries per block, same batch (8192 % 8 == 0)
    const int q0    = qbase + wave * 2;          // this wave's two queries
    const int b     = q0 / NPTS;
    const float* xb = x + (size_t)b * NPTS * CCH;

    // ---- load the two query vectors into registers (uniform per wave) ----
    float4 qa[8], qb[8];
    {
        const float4* p0 = (const float4*)(x + (size_t)q0 * CCH);
        const float4* p1 = (const float4*)(x + (size_t)(q0 + 1) * CCH);
        #pragma unroll
        for (int k = 0; k < 8; ++k) { qa[k] = p0[k]; qb[k] = p1[k]; }
    }

    // ---- per-lane exact top-16 lists, sorted ascending by (key, idx) ----
    float kdA[KNN], kdB[KNN];
    int   kiA[KNN], kiB[KNN];
    #pragma unroll
    for (int p = 0; p < KNN; ++p) {
        kdA[p] = INF; kdB[p] = INF;
        kiA[p] = 0x7fffffff; kiB[p] = 0x7fffffff;
    }

    auto insert = [&](float (&kd)[KNN], int (&ki)[KNN], float key, int j) {
        // entry guard: strictly better than current worst under (key, idx) order
        if (key < kd[KNN-1] || (key == kd[KNN-1] && j < ki[KNN-1])) {
            float ck = key; int cj = j;
            #pragma unroll
            for (int p = 0; p < KNN; ++p) {
                bool sw = (ck < kd[p]) || (ck == kd[p] && cj < ki[p]);
                float nk = sw ? ck : kd[p];
                int   nj = sw ? cj : ki[p];
                ck = sw ? kd[p] : ck;
                cj = sw ? ki[p] : cj;
                kd[p] = nk; ki[p] = nj;
            }
        }
    };

    // ---- stream candidate tiles through LDS ----
    for (int t = 0; t < NPTS / TILE; ++t) {
        __syncthreads();
        {   // cooperative load: each thread stages half a candidate row (16 floats)
            int row  = tid >> 1;
            int half = tid & 1;
            const float4* g = (const float4*)(xb + (size_t)(t * TILE + row) * CCH + half * 16);
            float4 v0 = g[0], v1 = g[1], v2 = g[2], v3 = g[3];
            float* d = &tile[row * TSTRIDE + half * 16];
            ((float4*)d)[0] = v0;
            ((float4*)d)[1] = v1;
            ((float4*)d)[2] = v2;
            ((float4*)d)[3] = v3;
            float sq = v0.x*v0.x + v0.y*v0.y + v0.z*v0.z + v0.w*v0.w
                     + v1.x*v1.x + v1.y*v1.y + v1.z*v1.z + v1.w*v1.w
                     + v2.x*v2.x + v2.y*v2.y + v2.z*v2.z + v2.w*v2.w
                     + v3.x*v3.x + v3.y*v3.y + v3.z*v3.z + v3.w*v3.w;
            sqbuf[half * TILE + row] = sq;
        }
        __syncthreads();

        #pragma unroll
        for (int s = 0; s < 2; ++s) {
            int ci = lane + s * 64;
            const float* cr = &tile[ci * TSTRIDE];
            float sq = sqbuf[ci] + sqbuf[TILE + ci];
            float aA0 = 0.f, aA1 = 0.f, aA2 = 0.f, aA3 = 0.f;
            float aB0 = 0.f, aB1 = 0.f, aB2 = 0.f, aB3 = 0.f;
            #pragma unroll
            for (int k = 0; k < 8; ++k) {
                float4 c = ((const float4*)cr)[k];
                aA0 = fmaf(c.x, qa[k].x, aA0);
                aA1 = fmaf(c.y, qa[k].y, aA1);
                aA2 = fmaf(c.z, qa[k].z, aA2);
                aA3 = fmaf(c.w, qa[k].w, aA3);
                aB0 = fmaf(c.x, qb[k].x, aB0);
                aB1 = fmaf(c.y, qb[k].y, aB1);
                aB2 = fmaf(c.z, qb[k].z, aB2);
                aB3 = fmaf(c.w, qb[k].w, aB3);
            }
            float dA = (aA0 + aA1) + (aA2 + aA3);
            float dB = (aB0 + aB1) + (aB2 + aB3);
            int j = t * TILE + ci;
            // key = sq_j - 2*dot ; query's own sq_i is a per-query constant -> same ordering
            insert(kdA, kiA, fmaf(-2.f, dA, sq), j);
            insert(kdB, kiB, fmaf(-2.f, dB, sq), j);
        }
    }

    // ---- wave-level tournament merge: exact global top-16 per query ----
    auto run_merge = [&](float (&kd)[KNN], int (&ki)[KNN], int qrow) {
        for (int r = 0; r < KNN; ++r) {
            float hk = kd[0]; int hj = ki[0];
            float ck = hk;    int cj = hj;
            #pragma unroll
            for (int off = 32; off > 0; off >>= 1) {
                float ok = __shfl_xor(ck, off, 64);
                int   oj = __shfl_xor(cj, off, 64);
                bool take = (ok < ck) || (ok == ck && oj < cj);
                ck = take ? ok : ck;
                cj = take ? oj : cj;
            }
            if (lane == 0) knn_idx[qrow][r] = cj;
            if (hj == cj) {   // exactly one lane pops (indices unique)
                #pragma unroll
                for (int p = 0; p < KNN - 1; ++p) { kd[p] = kd[p+1]; ki[p] = ki[p+1]; }
                kd[KNN-1] = INF; ki[KNN-1] = 0x7fffffff;
            }
        }
    };
    run_merge(kdA, kiA, wave * 2 + 0);
    run_merge(kdB, kiB, wave * 2 + 1);

    __syncthreads();

    // ---- gather + max-pool: thread (q = tid>>5, c = tid&31) ----
    {
        int q = tid >> 5, c = tid & 31;
        float m = -INF;
        #pragma unroll
        for (int k = 0; k < KNN; ++k) {
            int j = knn_idx[q][k];
            m = fmaxf(m, xb[(size_t)j * CCH + c]);
        }
        pooled[q][c] = m;
    }
    __syncthreads();

    // ---- linear: h[q][l] = pooled[q][:] @ Wl[:, l] + bl[l] ----
    {
        int l = tid & 63;
        int qh = tid >> 6;  // 0..3
        for (int qq = qh; qq < QPB; qq += 4) {
            float acc = bl[l];
            #pragma unroll
            for (int c = 0; c < CCH; ++c) acc = fmaf(pooled[qq][c], Wl[c * LDIM + l], acc);
            hbuf[qq][l] = acc;
        }
    }
    __syncthreads();

    // ---- conv1x1 + relu: out[q][o] = relu(h[q][:] @ Wc[:, o] + bc[o]) ----
    {
        int o = tid & 127;
        int qh = tid >> 7;  // 0..1
        for (int qq = qh; qq < QPB; qq += 2) {
            float acc = bc[o];
            #pragma unroll
            for (int l = 0; l < LDIM; ++l) acc = fmaf(hbuf[qq][l], Wc[l * ODIM + o], acc);
            out[(size_t)(qbase + qq) * ODIM + o] = fmaxf(acc, 0.f);
        }
    }
}

extern "C" void kernel_launch(void* const* d_in, const int* in_sizes, int n_in,
                              void* d_out, int out_size, void* d_ws, size_t ws_size,
                              hipStream_t stream) {
    const float* x  = (const float*)d_in[0];
    const float* Wl = (const float*)d_in[1];
    const float* bl = (const float*)d_in[2];
    const float* Wc = (const float*)d_in[3];
    const float* bc = (const float*)d_in[4];
    float* out = (float*)d_out;
    (void)in_sizes; (void)n_in; (void)out_size; (void)d_ws; (void)ws_size;

    dim3 grid(BN_TOTAL / QPB);
    dim3 block(256);
    hipLaunchKernelGGL(graph_layer_kernel, grid, block, 0, stream,
                       x, Wl, bl, Wc, bc, out);
}

// Round 2
// 887.750 us; speedup vs baseline: 2.7580x; 2.7580x over previous
//
#include <hip/hip_runtime.h>

#define NPTS  8192
#define CCH   32
#define LDIM  64
#define ODIM  128
#define KNN   16
#define QPB   64            // queries per block (one per lane)
#define CPW   2048          // candidates per wave (NPTS/4)
#define TSZ   32            // candidates per tile
#define NTILES (CPW/TSZ)    // 64

// LDS layout (overlaid phases):
//  phase1: stage  8 bufs x 1024 floats = 32768 B @0 ; sqt 256 floats = 1024 B @32768
//  phase2: mval 4*64*16 f = 16384 B @0 ; midx = 16384 B @16384 ; knn 64*16 int = 4096 B @36864
//  phase3: pooled 64*33 f = 8448 B @0 ; h 64*65 f = 16640 B @8448   (knn @36864 stays live)
#define LDS_BYTES 40960

__device__ __forceinline__ float dot4(float4 v) {
    return v.x*v.x + v.y*v.y + v.z*v.z + v.w*v.w;
}

__global__ __launch_bounds__(256, 4)
void graph_layer_kernel(const float* __restrict__ x,
                        const float* __restrict__ Wl,
                        const float* __restrict__ bl,
                        const float* __restrict__ Wc,
                        const float* __restrict__ bc,
                        float* __restrict__ out)
{
    __shared__ __align__(16) char lds[LDS_BYTES];
    float* st   = (float*)lds;                 // phase1 staging
    float* sqt  = (float*)(lds + 32768);       // phase1 sq per candidate
    float* mv   = (float*)lds;                 // phase2 merge values
    int*   mi   = (int*)(lds + 16384);         // phase2 merge indices
    int*   kn   = (int*)(lds + 36864);         // knn indices [64][16]
    float* pl   = (float*)lds;                 // phase3 pooled [64][33]
    float* hh   = (float*)(lds + 8448);        // phase3 hidden [64][65]

    const int tid  = threadIdx.x;
    const int lane = tid & 63;
    const int w    = tid >> 6;                 // wave id = candidate quarter
    const float INF = __builtin_inff();

    const int qb0 = blockIdx.x * QPB;          // 64 queries per block
    const int b   = qb0 / NPTS;
    const float* xb = x + (size_t)b * NPTS * CCH;
    const int cq0 = w * CPW;                   // this wave's candidate range base

    // ---- query vector for this lane's query ----
    float4 qv[8];
    {
        const float4* qp = (const float4*)(x + (size_t)(qb0 + lane) * CCH);
        #pragma unroll
        for (int k = 0; k < 8; ++k) qv[k] = qp[k];
    }

    // ---- per-lane top-16 (values-only ordering; indices carried) ----
    float kd[KNN]; int ki[KNN];
    #pragma unroll
    for (int p = 0; p < KNN; ++p) { kd[p] = INF; ki[p] = 0x7fffffff; }

    float* mybuf0 = st + (w * 2 + 0) * 1024;
    float* mybuf1 = st + (w * 2 + 1) * 1024;
    float* mysq0  = sqt + (w * 2 + 0) * TSZ;
    float* mysq1  = sqt + (w * 2 + 1) * TSZ;

    // stage tile 0 into buf0 (wave-private, no barriers needed)
    {
        const float4* g = (const float4*)(xb + (size_t)cq0 * CCH);
        float4 v0 = g[lane], v1 = g[64+lane], v2 = g[128+lane], v3 = g[192+lane];
        float s0 = dot4(v0), s1 = dot4(v1), s2 = dot4(v2), s3 = dot4(v3);
        #pragma unroll
        for (int m = 1; m <= 4; m <<= 1) {
            s0 += __shfl_xor(s0, m); s1 += __shfl_xor(s1, m);
            s2 += __shfl_xor(s2, m); s3 += __shfl_xor(s3, m);
        }
        ((float4*)mybuf0)[lane] = v0; ((float4*)mybuf0)[64+lane] = v1;
        ((float4*)mybuf0)[128+lane] = v2; ((float4*)mybuf0)[192+lane] = v3;
        if ((lane & 7) == 0) {
            int g8 = lane >> 3;
            mysq0[g8] = s0; mysq0[8+g8] = s1; mysq0[16+g8] = s2; mysq0[24+g8] = s3;
        }
    }

    for (int T = 0; T < NTILES; ++T) {
        // issue global loads for next tile (overlap with compute below)
        int Tn = (T + 1 < NTILES) ? T + 1 : NTILES - 1;
        const float4* g = (const float4*)(xb + (size_t)(cq0 + Tn * TSZ) * CCH);
        float4 v0 = g[lane], v1 = g[64+lane], v2 = g[128+lane], v3 = g[192+lane];

        // compute on current buffer
        const float4* cb = (const float4*)((T & 1) ? mybuf1 : mybuf0);
        const float*  sq = (T & 1) ? mysq1 : mysq0;
        #pragma unroll 2
        for (int c = 0; c < TSZ; ++c) {
            float4 c0 = cb[c*8+0], c1 = cb[c*8+1], c2 = cb[c*8+2], c3 = cb[c*8+3];
            float4 c4 = cb[c*8+4], c5 = cb[c*8+5], c6 = cb[c*8+6], c7 = cb[c*8+7];
            float a0 = 0.f, a1 = 0.f, a2 = 0.f, a3 = 0.f;
            a0 = fmaf(c0.x, qv[0].x, a0); a1 = fmaf(c0.y, qv[0].y, a1);
            a2 = fmaf(c0.z, qv[0].z, a2); a3 = fmaf(c0.w, qv[0].w, a3);
            a0 = fmaf(c1.x, qv[1].x, a0); a1 = fmaf(c1.y, qv[1].y, a1);
            a2 = fmaf(c1.z, qv[1].z, a2); a3 = fmaf(c1.w, qv[1].w, a3);
            a0 = fmaf(c2.x, qv[2].x, a0); a1 = fmaf(c2.y, qv[2].y, a1);
            a2 = fmaf(c2.z, qv[2].z, a2); a3 = fmaf(c2.w, qv[2].w, a3);
            a0 = fmaf(c3.x, qv[3].x, a0); a1 = fmaf(c3.y, qv[3].y, a1);
            a2 = fmaf(c3.z, qv[3].z, a2); a3 = fmaf(c3.w, qv[3].w, a3);
            a0 = fmaf(c4.x, qv[4].x, a0); a1 = fmaf(c4.y, qv[4].y, a1);
            a2 = fmaf(c4.z, qv[4].z, a2); a3 = fmaf(c4.w, qv[4].w, a3);
            a0 = fmaf(c5.x, qv[5].x, a0); a1 = fmaf(c5.y, qv[5].y, a1);
            a2 = fmaf(c5.z, qv[5].z, a2); a3 = fmaf(c5.w, qv[5].w, a3);
            a0 = fmaf(c6.x, qv[6].x, a0); a1 = fmaf(c6.y, qv[6].y, a1);
            a2 = fmaf(c6.z, qv[6].z, a2); a3 = fmaf(c6.w, qv[6].w, a3);
            a0 = fmaf(c7.x, qv[7].x, a0); a1 = fmaf(c7.y, qv[7].y, a1);
            a2 = fmaf(c7.z, qv[7].z, a2); a3 = fmaf(c7.w, qv[7].w, a3);
            float dot = (a0 + a1) + (a2 + a3);
            float key = fmaf(-2.f, dot, sq[c]);
            int j = cq0 + T * TSZ + c;
            if (key < kd[KNN-1]) {   // values-only sorted insert
                float ck = key; int cj = j;
                #pragma unroll
                for (int p = 0; p < KNN; ++p) {
                    bool sw = ck < kd[p];
                    float nk = sw ? ck : kd[p];
                    int   nj = sw ? cj : ki[p];
                    ck = sw ? kd[p] : ck;
                    cj = sw ? ki[p] : cj;
                    kd[p] = nk; ki[p] = nj;
                }
            }
        }

        // finish staging next tile (sq shuffles + LDS writes; waits vmcnt here)
        float s0 = dot4(v0), s1 = dot4(v1), s2 = dot4(v2), s3 = dot4(v3);
        #pragma unroll
        for (int m = 1; m <= 4; m <<= 1) {
            s0 += __shfl_xor(s0, m); s1 += __shfl_xor(s1, m);
            s2 += __shfl_xor(s2, m); s3 += __shfl_xor(s3, m);
        }
        float* nb  = ((T + 1) & 1) ? mybuf1 : mybuf0;
        float* nsq = ((T + 1) & 1) ? mysq1  : mysq0;
        ((float4*)nb)[lane] = v0; ((float4*)nb)[64+lane] = v1;
        ((float4*)nb)[128+lane] = v2; ((float4*)nb)[192+lane] = v3;
        if ((lane & 7) == 0) {
            int g8 = lane >> 3;
            nsq[g8] = s0; nsq[8+g8] = s1; nsq[16+g8] = s2; nsq[24+g8] = s3;
        }
    }

    __syncthreads();   // all waves done reading stage region

    // ---- write per-wave partial top-16 lists ----
    #pragma unroll
    for (int p = 0; p < KNN; ++p) {
        mv[(w * 64 + lane) * KNN + p] = kd[p];
        mi[(w * 64 + lane) * KNN + p] = ki[p];
    }
    __syncthreads();

    // ---- 4-way merge (64 threads, one per query) ----
    if (tid < QPB) {
        int p0 = 0, p1 = 0, p2 = 0, p3 = 0;
        for (int r = 0; r < KNN; ++r) {
            float v0 = mv[(0 * 64 + tid) * KNN + p0];
            float v1 = mv[(1 * 64 + tid) * KNN + p1];
            float v2 = mv[(2 * 64 + tid) * KNN + p2];
            float v3 = mv[(3 * 64 + tid) * KNN + p3];
            int sel = 0; float bv = v0;
            if (v1 < bv) { bv = v1; sel = 1; }
            if (v2 < bv) { bv = v2; sel = 2; }
            if (v3 < bv) { bv = v3; sel = 3; }
            int ps = (sel == 0) ? p0 : (sel == 1) ? p1 : (sel == 2) ? p2 : p3;
            kn[tid * KNN + r] = mi[(sel * 64 + tid) * KNN + ps];
            p0 += (sel == 0); p1 += (sel == 1); p2 += (sel == 2); p3 += (sel == 3);
        }
    }
    __syncthreads();

    // ---- gather + max-pool: thread (q = tid>>2, part = tid&3 -> 8 channels) ----
    {
        int q = tid >> 2, part = tid & 3;
        float4 m0 = make_float4(-INF, -INF, -INF, -INF);
        float4 m1 = m0;
        #pragma unroll
        for (int k = 0; k < KNN; ++k) {
            int j = kn[q * KNN + k];
            const float4* r = (const float4*)(xb + (size_t)j * CCH + part * 8);
            float4 r0 = r[0], r1 = r[1];
            m0.x = fmaxf(m0.x, r0.x); m0.y = fmaxf(m0.y, r0.y);
            m0.z = fmaxf(m0.z, r0.z); m0.w = fmaxf(m0.w, r0.w);
            m1.x = fmaxf(m1.x, r1.x); m1.y = fmaxf(m1.y, r1.y);
            m1.z = fmaxf(m1.z, r1.z); m1.w = fmaxf(m1.w, r1.w);
        }
        float* d = pl + q * 33 + part * 8;
        d[0] = m0.x; d[1] = m0.y; d[2] = m0.z; d[3] = m0.w;
        d[4] = m1.x; d[5] = m1.y; d[6] = m1.z; d[7] = m1.w;
    }
    __syncthreads();

    // ---- linear: h[q][l], thread: q = tid&63, l-range = (tid>>6)*16 .. +16 ----
    {
        int q = tid & 63, lg = tid >> 6;
        #pragma unroll
        for (int l = lg * 16; l < lg * 16 + 16; ++l) {
            float acc = bl[l];
            #pragma unroll
            for (int c = 0; c < CCH; ++c)
                acc = fmaf(pl[q * 33 + c], Wl[c * LDIM + l], acc);
            hh[q * 65 + l] = acc;
        }
    }
    __syncthreads();

    // ---- conv1x1 + relu: wave wq covers queries wq*16..+16, lane = o-pair ----
    {
        int o2 = tid & 63, wq = tid >> 6;
        float acc[32];
        float2 bcv = ((const float2*)bc)[o2];
        #pragma unroll
        for (int i = 0; i < 16; ++i) { acc[2*i] = bcv.x; acc[2*i+1] = bcv.y; }
        for (int l = 0; l < LDIM; ++l) {
            float2 wc = ((const float2*)(Wc + (size_t)l * ODIM))[o2];
            #pragma unroll
            for (int i = 0; i < 16; ++i) {
                float hv = hh[(wq * 16 + i) * 65 + l];
                acc[2*i]   = fmaf(hv, wc.x, acc[2*i]);
                acc[2*i+1] = fmaf(hv, wc.y, acc[2*i+1]);
            }
        }
        #pragma unroll
        for (int i = 0; i < 16; ++i) {
            float2 r;
            r.x = fmaxf(acc[2*i],   0.f);
            r.y = fmaxf(acc[2*i+1], 0.f);
            ((float2*)(out + (size_t)(qb0 + wq * 16 + i) * ODIM))[o2] = r;
        }
    }
}

extern "C" void kernel_launch(void* const* d_in, const int* in_sizes, int n_in,
                              void* d_out, int out_size, void* d_ws, size_t ws_size,
                              hipStream_t stream) {
    const float* x  = (const float*)d_in[0];
    const float* Wl = (const float*)d_in[1];
    const float* bl = (const float*)d_in[2];
    const float* Wc = (const float*)d_in[3];
    const float* bc = (const float*)d_in[4];
    float* out = (float*)d_out;
    (void)in_sizes; (void)n_in; (void)out_size; (void)d_ws; (void)ws_size;

    dim3 grid((4 * NPTS) / QPB);   // 512 blocks
    dim3 block(256);
    hipLaunchKernelGGL(graph_layer_kernel, grid, block, 0, stream,
                       x, Wl, bl, Wc, bc, out);
}

// Round 3
// 751.643 us; speedup vs baseline: 3.2574x; 1.1811x over previous
//
#include <hip/hip_runtime.h>

#define NPTS   8192
#define CCH    32
#define LDIM   64
#define ODIM   128
#define KNN    16
#define TILEC  256                 // candidates per LDS tile
#define NTIL   (NPTS / TILEC)      // 32
#define QPB    16                  // queries per block (4 waves x 4)
#define NBLK   ((4 * NPTS) / QPB)  // 2048 blocks

typedef const __attribute__((address_space(1))) void* gas_ptr;
typedef __attribute__((address_space(3))) void* las_ptr;

// Prologue: squared norms of all 32768 points into d_ws.
__global__ void sq_kernel(const float* __restrict__ x, float* __restrict__ sqg) {
    int i = blockIdx.x * 256 + threadIdx.x;
    const float4* p = (const float4*)(x + (size_t)i * CCH);
    float s = 0.f;
    #pragma unroll
    for (int k = 0; k < 8; ++k) {
        float4 v = p[k];
        s += v.x * v.x + v.y * v.y + v.z * v.z + v.w * v.w;
    }
    sqg[i] = s;
}

// LDS: double-buffered candidate tiles (chunk-major float4 [k:0..7][c:0..255])
//   bufA @0 (32 KB), bufB @32768 (32 KB), sqsA @65536 (1 KB), sqsB @66560 (1 KB)
// epilogue overlay: kn @0 (1 KB), pooled @1024 (16*33 f), hh @3136 (16*65 f)
__global__ __launch_bounds__(256, 2)
void graph_layer_kernel(const float* __restrict__ x,
                        const float* __restrict__ sqg,
                        const float* __restrict__ Wl,
                        const float* __restrict__ bl,
                        const float* __restrict__ Wc,
                        const float* __restrict__ bc,
                        float* __restrict__ out)
{
    __shared__ __align__(16) char smem[67584];
    float4* bufA = (float4*)smem;
    float4* bufB = (float4*)(smem + 32768);
    float*  sqsA = (float*)(smem + 65536);
    float*  sqsB = (float*)(smem + 66560);
    int*    kn   = (int*)smem;                 // [16][16] neighbor idx
    float*  pl   = (float*)(smem + 1024);      // [16][33] pooled
    float*  hh   = (float*)(smem + 3136);      // [16][65] hidden

    const int tid  = threadIdx.x;
    const int lane = tid & 63;
    const int w    = tid >> 6;
    const float INF = __builtin_inff();

    const int qb0 = blockIdx.x * QPB;
    const int b   = qb0 >> 13;                 // qb0 / 8192
    const float* xb  = x   + (size_t)(b << 13) * CCH;
    const float* sqb = sqg + (b << 13);

    // ---- 4 shared queries per wave, replicated in registers ----
    float4 q0[8], q1[8], q2[8], q3[8];
    {
        const float4* p0 = (const float4*)(x + (size_t)(qb0 + w * 4 + 0) * CCH);
        const float4* p1 = (const float4*)(x + (size_t)(qb0 + w * 4 + 1) * CCH);
        const float4* p2 = (const float4*)(x + (size_t)(qb0 + w * 4 + 2) * CCH);
        const float4* p3 = (const float4*)(x + (size_t)(qb0 + w * 4 + 3) * CCH);
        #pragma unroll
        for (int k = 0; k < 8; ++k) { q0[k] = p0[k]; q1[k] = p1[k]; q2[k] = p2[k]; q3[k] = p3[k]; }
    }

    // distributed sorted-16 per query: query g's list in lanes g*16..g*16+15
    float selk = INF;
    int   seli = 0;
    float T0 = INF, T1 = INF, T2 = INF, T3 = INF;

    auto stage = [&](int T, float4* bf, float* sqs) {
        // thread t stages candidate (T*256+t): chunk i -> float4 slot i*256+t
        const float* gsrc = xb + (size_t)(T * TILEC + tid) * CCH;
        char* lbase = (char*)bf + tid * 16;
        #pragma unroll
        for (int i = 0; i < 8; ++i) {
            __builtin_amdgcn_global_load_lds((gas_ptr)(gsrc + i * 4),
                                             (las_ptr)(lbase + i * 4096), 16, 0, 0);
        }
        __builtin_amdgcn_global_load_lds((gas_ptr)(sqb + T * TILEC + tid),
                                         (las_ptr)(sqs + tid), 4, 0, 0);
    };

    auto sel_insert = [&](float key, float& Tref, int gsel, int cbase) {
        unsigned long long m = __ballot(key < Tref);
        if (m) {
            const bool ing = (lane >> 4) == gsel;
            do {
                int src = __ffsll(m) - 1;          // ascending lane = ascending idx
                float nk = __shfl(key, src);
                int   ni = cbase + src;
                float upk = __shfl_up(selk, 1);
                int   upi = __shfl_up(seli, 1);
                bool pme   = nk < selk;            // strict <: lower idx wins ties
                bool pprev = (nk < upk) && ((lane & 15) != 0);
                float rk = pme ? (pprev ? upk : nk) : selk;
                int   ri = pme ? (pprev ? upi : ni) : seli;
                if (ing) { selk = rk; seli = ri; }
                m &= (m - 1);
            } while (m);
            Tref = __shfl(selk, gsel * 16 + 15);   // new 16th-best threshold
        }
    };

    // ---- scan all 8192 candidates, double-buffered DMA tiles ----
    stage(0, bufA, sqsA);
    __syncthreads();
    #pragma unroll 1
    for (int T = 0; T < NTIL; ++T) {
        const bool cur = T & 1;
        if (T + 1 < NTIL) stage(T + 1, cur ? bufA : bufB, cur ? sqsA : sqsB);
        const float4* cb = cur ? bufB : bufA;
        const float*  sv = cur ? sqsB : sqsA;
        #pragma unroll 1
        for (int s = 0; s < 4; ++s) {
            const int cl = s * 64 + lane;          // lane's candidate in tile
            float a0 = 0.f, a1 = 0.f, a2 = 0.f, a3 = 0.f;
            #pragma unroll
            for (int k = 0; k < 8; ++k) {
                float4 cv = cb[k * 256 + cl];      // stride-16B across lanes: conflict-free
                a0 = fmaf(cv.x, q0[k].x, a0); a0 = fmaf(cv.y, q0[k].y, a0);
                a0 = fmaf(cv.z, q0[k].z, a0); a0 = fmaf(cv.w, q0[k].w, a0);
                a1 = fmaf(cv.x, q1[k].x, a1); a1 = fmaf(cv.y, q1[k].y, a1);
                a1 = fmaf(cv.z, q1[k].z, a1); a1 = fmaf(cv.w, q1[k].w, a1);
                a2 = fmaf(cv.x, q2[k].x, a2); a2 = fmaf(cv.y, q2[k].y, a2);
                a2 = fmaf(cv.z, q2[k].z, a2); a2 = fmaf(cv.w, q2[k].w, a2);
                a3 = fmaf(cv.x, q3[k].x, a3); a3 = fmaf(cv.y, q3[k].y, a3);
                a3 = fmaf(cv.z, q3[k].z, a3); a3 = fmaf(cv.w, q3[k].w, a3);
            }
            const float sqv = sv[cl];
            float k0 = fmaf(-2.f, a0, sqv);        // key = sq_j - 2*dot (same order per query)
            float k1 = fmaf(-2.f, a1, sqv);
            float k2 = fmaf(-2.f, a2, sqv);
            float k3 = fmaf(-2.f, a3, sqv);
            const int cbase = T * TILEC + s * 64;
            sel_insert(k0, T0, 0, cbase);
            sel_insert(k1, T1, 1, cbase);
            sel_insert(k2, T2, 2, cbase);
            sel_insert(k3, T3, 3, cbase);
        }
        __syncthreads();
    }

    // ---- write knn indices (each lane holds exactly one (query, rank)) ----
    kn[(w * 4 + (lane >> 4)) * KNN + (lane & 15)] = seli;
    __syncthreads();

    // ---- gather + max-pool: thread -> (q = tid>>4, channels 2*(tid&15)..+1) ----
    {
        int q = tid >> 4, c2 = (tid & 15) * 2;
        float m0 = -INF, m1 = -INF;
        #pragma unroll
        for (int k = 0; k < KNN; ++k) {
            int j = kn[q * KNN + k];
            float2 v = *(const float2*)(xb + (size_t)j * CCH + c2);
            m0 = fmaxf(m0, v.x); m1 = fmaxf(m1, v.y);
        }
        pl[q * 33 + c2] = m0; pl[q * 33 + c2 + 1] = m1;
    }
    __syncthreads();

    // ---- linear 32->64 ----
    {
        int l = tid & 63, qg = tid >> 6;
        #pragma unroll 1
        for (int q = qg; q < QPB; q += 4) {
            float acc = bl[l];
            #pragma unroll
            for (int c = 0; c < CCH; ++c)
                acc = fmaf(pl[q * 33 + c], Wl[c * LDIM + l], acc);
            hh[q * 65 + l] = acc;
        }
    }
    __syncthreads();

    // ---- conv1x1 64->128 + relu ----
    {
        int o = tid & 127, qh = tid >> 7;
        #pragma unroll 1
        for (int q = qh; q < QPB; q += 2) {
            float acc = bc[o];
            #pragma unroll
            for (int l = 0; l < LDIM; ++l)
                acc = fmaf(hh[q * 65 + l], Wc[l * ODIM + o], acc);
            out[(size_t)(qb0 + q) * ODIM + o] = fmaxf(acc, 0.f);
        }
    }
}

extern "C" void kernel_launch(void* const* d_in, const int* in_sizes, int n_in,
                              void* d_out, int out_size, void* d_ws, size_t ws_size,
                              hipStream_t stream) {
    const float* x  = (const float*)d_in[0];
    const float* Wl = (const float*)d_in[1];
    const float* bl = (const float*)d_in[2];
    const float* Wc = (const float*)d_in[3];
    const float* bc = (const float*)d_in[4];
    float* out = (float*)d_out;
    float* sqf = (float*)d_ws;                 // 32768 floats = 128 KB
    (void)in_sizes; (void)n_in; (void)out_size; (void)ws_size;

    hipLaunchKernelGGL(sq_kernel, dim3((4 * NPTS) / 256), dim3(256), 0, stream, x, sqf);
    hipLaunchKernelGGL(graph_layer_kernel, dim3(NBLK), dim3(256), 0, stream,
                       x, sqf, Wl, bl, Wc, bc, out);
}